// Round 4
// baseline (327.516 us; speedup 1.0000x reference)
//
#include <hip/hip_runtime.h>
#include <math.h>

#define BATCH 256
#define QL 50
#define EMB 50
#define DL 2000
#define NB 11
#define SEG 8        // d-dimension split per batch -> 2048 blocks
#define RPB 250      // rows per block (DL/SEG)
#define TPB 256

// ---------------- main kernel: cosine sim + histogram ----------------
// e-outer / q-inner, 50 RMW accumulators per thread (remat-proof, R3-proven).
// Q operands come straight from global at wave-uniform addresses with
// compile-time offsets -> s_load into SGPRs (scalar pipe), so the main loop
// has ZERO LDS traffic (R3's 52us/CU LDS-read bottleneck removed).
// e16 macro-steps: one 64B line per d-row per step, fetched once, fully
// consumed -> no L1-capacity over-fetch (R3: 2.3x).
__global__ __launch_bounds__(TPB, 4)
void sim_hist_kernel(const float* __restrict__ qe,   // [B,QL,EMB]
                     const float* __restrict__ de,   // [B,DL,EMB]
                     const int*   __restrict__ qid,  // [B,QL]
                     const int*   __restrict__ did,  // [B,DL]
                     unsigned*    __restrict__ g_hist) // [B,QL,NB]
{
    const int bid = blockIdx.x;
    const int b   = bid >> 3;
    const int seg = bid & 7;
    const int t   = threadIdx.x;

    __shared__ float    s_qrn[QL];
    __shared__ int      s_qv[QL];
    __shared__ unsigned s_hist[QL * NB];

    const float* __restrict__ qbase = qe + (size_t)b * QL * EMB;

    for (int i = t; i < QL * NB; i += TPB) s_hist[i] = 0u;
    if (t < QL) {
        const float* qr = qbase + t * EMB;
        float ss = 0.f;
        #pragma unroll
        for (int e = 0; e < EMB; ++e) ss = fmaf(qr[e], qr[e], ss);
        s_qrn[t] = 1.0f / (sqrtf(ss) + 1e-8f);
        s_qv[t]  = (qid[(size_t)b * QL + t] > 0) ? 1 : 0;
    }
    __syncthreads();

    // this thread's single d row
    const bool ok  = (t < RPB);
    const int  row = seg * RPB + (ok ? t : 0);
    const float* __restrict__ dr = de + ((size_t)b * DL + row) * EMB;
    const int dval = (ok && did[(size_t)b * DL + row] > 0) ? 1 : 0;

    float acc[QL];
    #pragma unroll
    for (int q = 0; q < QL; ++q) acc[q] = 0.f;
    float ss = 0.f;

    // ---- main loop: 3 e16 macro-steps (e = 0..47) ----
    #pragma unroll 1
    for (int m = 0; m < 3; ++m) {
        const int e0 = m * 16;
        float d[16];
        #pragma unroll
        for (int j = 0; j < 8; ++j) {          // one 64B line per row, 8B-aligned
            const float2 v = *(const float2*)(dr + e0 + 2 * j);
            d[2 * j]     = v.x;
            d[2 * j + 1] = v.y;
        }
        #pragma unroll
        for (int j = 0; j < 16; ++j) ss = fmaf(d[j], d[j], ss);  // e-ascending (R3 order)

        #pragma unroll
        for (int q = 0; q < QL; ++q) {
            // wave-uniform address, compile-time offset -> s_load + v_fmac(sgpr)
            const float* qr = qbase + q * EMB + e0;
            float a = acc[q];
            #pragma unroll
            for (int j = 0; j < 8; ++j) {
                const float2 qv = *(const float2*)(qr + 2 * j);
                a = fmaf(d[2 * j],     qv.x, a);
                a = fmaf(d[2 * j + 1], qv.y, a);
            }
            acc[q] = a;
        }
    }
    // ---- tail: e = 48,49 ----
    {
        const float2 v = *(const float2*)(dr + 48);
        ss = fmaf(v.x, v.x, ss);
        ss = fmaf(v.y, v.y, ss);
        #pragma unroll
        for (int q = 0; q < QL; ++q) {
            const float2 qv = *(const float2*)(qbase + q * EMB + 48);
            float a = acc[q];
            a = fmaf(v.x, qv.x, a);
            a = fmaf(v.y, qv.y, a);
            acc[q] = a;
        }
    }

    const float drn = 1.0f / (sqrtf(ss) + 1e-8f);

    // ---- histogram epilogue: LDS atomics (LDS pipe is idle now; block
    // stagger overlaps this with other blocks' FMA phase) ----
    #pragma unroll
    for (int q = 0; q < QL; ++q) {
        if (!s_qv[q]) continue;                 // wave-uniform skip
        const float s  = acc[q] * s_qrn[q] * drn;
        const float tt = ((s + 1.000001f) * 0.5f) * 10.0f;  // match ref eval order
        int bb = (int)tt;                       // trunc toward zero (np int32 cast)
        bb = bb < 0 ? 0 : (bb > 10 ? 10 : bb);
        if (dval) atomicAdd(&s_hist[q * NB + bb], 1u);
    }

    __syncthreads();
    for (int i = t; i < QL * NB; i += TPB) {
        const unsigned c = s_hist[i];
        if (c) atomicAdd(&g_hist[(size_t)b * QL * NB + i], c);
    }
}

// ---------------- epilogue 1: ffn dot + gate dot per batch ----------------
__global__ __launch_bounds__(TPB)
void ffn_gate_kernel(const unsigned* __restrict__ g_hist,
                     const float* __restrict__ W1,
                     const float* __restrict__ bias,
                     const float* __restrict__ qe,
                     const float* __restrict__ Wg,
                     float* __restrict__ ffn,
                     float* __restrict__ gate)
{
    const int b = blockIdx.x;
    const int t = threadIdx.x;

    float a1 = 0.f;
    for (int i = t; i < QL * NB; i += TPB)
        a1 = fmaf(logf((float)g_hist[(size_t)b * QL * NB + i] + 1e-5f), W1[i], a1);

    float a2 = 0.f;
    for (int i = t; i < QL * EMB; i += TPB)
        a2 = fmaf(qe[(size_t)b * QL * EMB + i], Wg[i], a2);

    #pragma unroll
    for (int off = 32; off > 0; off >>= 1) {
        a1 += __shfl_down(a1, off, 64);
        a2 += __shfl_down(a2, off, 64);
    }
    __shared__ float r1s[4], r2s[4];
    if ((t & 63) == 0) { r1s[t >> 6] = a1; r2s[t >> 6] = a2; }
    __syncthreads();
    if (t == 0) {
        ffn[b]  = r1s[0] + r1s[1] + r1s[2] + r1s[3] + bias[0];
        gate[b] = r2s[0] + r2s[1] + r2s[2] + r2s[3];
    }
}

// ---------------- epilogue 2: softmax over batch + final score ----------------
__global__ __launch_bounds__(TPB)
void score_kernel(const float* __restrict__ ffn,
                  const float* __restrict__ gate,
                  float* __restrict__ out)
{
    const int t = threadIdx.x;  // one block of 256 == BATCH
    __shared__ float buf[4];
    __shared__ float sM, sZ, sS;

    const float g = gate[t];

    float m = g;
    #pragma unroll
    for (int off = 32; off > 0; off >>= 1) m = fmaxf(m, __shfl_down(m, off, 64));
    if ((t & 63) == 0) buf[t >> 6] = m;
    __syncthreads();
    if (t == 0) sM = fmaxf(fmaxf(buf[0], buf[1]), fmaxf(buf[2], buf[3]));
    __syncthreads();

    const float e = expf(g - sM);
    float z = e;
    #pragma unroll
    for (int off = 32; off > 0; off >>= 1) z += __shfl_down(z, off, 64);
    __syncthreads();
    if ((t & 63) == 0) buf[t >> 6] = z;
    __syncthreads();
    if (t == 0) sZ = buf[0] + buf[1] + buf[2] + buf[3];
    __syncthreads();

    float p = e / sZ;           // out_tgn[t]
    float s = p;
    #pragma unroll
    for (int off = 32; off > 0; off >>= 1) s += __shfl_down(s, off, 64);
    __syncthreads();
    if ((t & 63) == 0) buf[t >> 6] = s;
    __syncthreads();
    if (t == 0) sS = buf[0] + buf[1] + buf[2] + buf[3];   // == sum(softmax) ~ 1
    __syncthreads();

    out[t] = ffn[t] * sS;
}

// ---------------- launcher ----------------
extern "C" void kernel_launch(void* const* d_in, const int* in_sizes, int n_in,
                              void* d_out, int out_size, void* d_ws, size_t ws_size,
                              hipStream_t stream)
{
    const float* qe  = (const float*)d_in[0];
    const float* de  = (const float*)d_in[1];
    const float* W1  = (const float*)d_in[2];
    const float* b1  = (const float*)d_in[3];
    const float* Wg  = (const float*)d_in[4];
    const int*   qid = (const int*)d_in[5];
    const int*   did = (const int*)d_in[6];
    float* out = (float*)d_out;

    unsigned* g_hist = (unsigned*)d_ws;
    const size_t hist_bytes = (size_t)BATCH * QL * NB * sizeof(unsigned); // 563,200 B
    float* ffn  = (float*)((char*)d_ws + hist_bytes);
    float* gate = ffn + BATCH;

    hipMemsetAsync(g_hist, 0, hist_bytes, stream);
    sim_hist_kernel<<<BATCH * SEG, TPB, 0, stream>>>(qe, de, qid, did, g_hist);
    ffn_gate_kernel<<<BATCH, TPB, 0, stream>>>(g_hist, W1, b1, qe, Wg, ffn, gate);
    score_kernel<<<1, TPB, 0, stream>>>(ffn, gate, out);
}

// Round 5
// 317.270 us; speedup vs baseline: 1.0323x; 1.0323x over previous
//
#include <hip/hip_runtime.h>
#include <math.h>

#define BATCH 256
#define QL 50
#define EMB 50
#define DL 2000
#define NB 11
#define SEG 8        // d-dimension split per batch -> 2048 blocks
#define RPB 250      // rows per block (DL/SEG)
#define TPB 256
#define SUB 4        // histogram sub-bins (split hot-bin atomic serialization)

// ---------------- main kernel: cosine sim + histogram ----------------
// e-outer / q-inner, 50 RMW accumulators per thread. Q operands from global
// at wave-uniform compile-time offsets -> s_load (scalar pipe, SGPR=112 in R4
// confirmed). launch_bounds min-waves MUST stay 2: R4's (,4) capped VGPRs at
// 128 and spilled the accumulators to scratch (VGPR=48, +20MB WRITE, 200us).
__global__ __launch_bounds__(TPB, 2)
void sim_hist_kernel(const float* __restrict__ qe,   // [B,QL,EMB]
                     const float* __restrict__ de,   // [B,DL,EMB]
                     const int*   __restrict__ qid,  // [B,QL]
                     const int*   __restrict__ did,  // [B,DL]
                     unsigned*    __restrict__ g_hist) // [B,QL,NB]
{
    const int bid = blockIdx.x;
    const int b   = bid >> 3;
    const int seg = bid & 7;
    const int t   = threadIdx.x;

    __shared__ float    s_qrn[QL];
    __shared__ int      s_qv[QL];
    __shared__ unsigned s_hist[QL * NB * SUB];   // [q][bin][sub] -> adjacent banks

    const float* __restrict__ qbase = qe + (size_t)b * QL * EMB;

    for (int i = t; i < QL * NB * SUB; i += TPB) s_hist[i] = 0u;
    if (t < QL) {
        const float* qr = qbase + t * EMB;
        float ss = 0.f;
        #pragma unroll
        for (int e = 0; e < EMB; ++e) ss = fmaf(qr[e], qr[e], ss);
        s_qrn[t] = 1.0f / (sqrtf(ss) + 1e-8f);
        s_qv[t]  = (qid[(size_t)b * QL + t] > 0) ? 1 : 0;
    }
    __syncthreads();

    // this thread's single d row
    const bool ok  = (t < RPB);
    const int  row = seg * RPB + (ok ? t : 0);
    const float* __restrict__ dr = de + ((size_t)b * DL + row) * EMB;
    const int dval = (ok && did[(size_t)b * DL + row] > 0) ? 1 : 0;

    float acc[QL];
    #pragma unroll
    for (int q = 0; q < QL; ++q) acc[q] = 0.f;
    float ss = 0.f;

    // ---- main loop: 3 e16 macro-steps (e = 0..47) ----
    #pragma unroll 1
    for (int m = 0; m < 3; ++m) {
        const int e0 = m * 16;
        float d[16];
        #pragma unroll
        for (int j = 0; j < 8; ++j) {
            const float2 v = *(const float2*)(dr + e0 + 2 * j);
            d[2 * j]     = v.x;
            d[2 * j + 1] = v.y;
        }
        #pragma unroll
        for (int j = 0; j < 16; ++j) ss = fmaf(d[j], d[j], ss);  // e-ascending order

        #pragma unroll
        for (int q = 0; q < QL; ++q) {
            // wave-uniform address, compile-time offset -> s_load + v_fmac(sgpr)
            const float* qr = qbase + q * EMB + e0;
            float a = acc[q];
            #pragma unroll
            for (int j = 0; j < 8; ++j) {
                const float2 qv = *(const float2*)(qr + 2 * j);
                a = fmaf(d[2 * j],     qv.x, a);
                a = fmaf(d[2 * j + 1], qv.y, a);
            }
            acc[q] = a;
        }
    }
    // ---- tail: e = 48,49 ----
    {
        const float2 v = *(const float2*)(dr + 48);
        ss = fmaf(v.x, v.x, ss);
        ss = fmaf(v.y, v.y, ss);
        #pragma unroll
        for (int q = 0; q < QL; ++q) {
            const float2 qv = *(const float2*)(qbase + q * EMB + 48);
            float a = acc[q];
            a = fmaf(v.x, qv.x, a);
            a = fmaf(v.y, qv.y, a);
            acc[q] = a;
        }
    }

    const float drn = 1.0f / (sqrtf(ss) + 1e-8f);

    // ---- histogram epilogue: 4-way sub-binned LDS atomics.
    // ~25 of 64 lanes hit the central bin per q (R3/R4: 45k conflict-cyc/CU);
    // lane>>4 spreads the same-address serialization over 4 adjacent banks.
    const int sub = (t >> 4) & (SUB - 1);
    #pragma unroll
    for (int q = 0; q < QL; ++q) {
        if (!s_qv[q]) continue;                 // wave-uniform skip
        const float s  = acc[q] * s_qrn[q] * drn;
        const float tt = ((s + 1.000001f) * 0.5f) * 10.0f;  // match ref eval order
        int bb = (int)tt;                       // trunc toward zero (np int32 cast)
        bb = bb < 0 ? 0 : (bb > 10 ? 10 : bb);
        if (dval) atomicAdd(&s_hist[(q * NB + bb) * SUB + sub], 1u);
    }

    __syncthreads();
    for (int i = t; i < QL * NB; i += TPB) {
        const unsigned c = s_hist[i * SUB] + s_hist[i * SUB + 1]
                         + s_hist[i * SUB + 2] + s_hist[i * SUB + 3];
        if (c) atomicAdd(&g_hist[(size_t)b * QL * NB + i], c);
    }
}

// ---------------- epilogue 1: ffn dot + gate dot per batch ----------------
__global__ __launch_bounds__(TPB)
void ffn_gate_kernel(const unsigned* __restrict__ g_hist,
                     const float* __restrict__ W1,
                     const float* __restrict__ bias,
                     const float* __restrict__ qe,
                     const float* __restrict__ Wg,
                     float* __restrict__ ffn,
                     float* __restrict__ gate)
{
    const int b = blockIdx.x;
    const int t = threadIdx.x;

    float a1 = 0.f;
    for (int i = t; i < QL * NB; i += TPB)
        a1 = fmaf(logf((float)g_hist[(size_t)b * QL * NB + i] + 1e-5f), W1[i], a1);

    float a2 = 0.f;
    for (int i = t; i < QL * EMB; i += TPB)
        a2 = fmaf(qe[(size_t)b * QL * EMB + i], Wg[i], a2);

    #pragma unroll
    for (int off = 32; off > 0; off >>= 1) {
        a1 += __shfl_down(a1, off, 64);
        a2 += __shfl_down(a2, off, 64);
    }
    __shared__ float r1s[4], r2s[4];
    if ((t & 63) == 0) { r1s[t >> 6] = a1; r2s[t >> 6] = a2; }
    __syncthreads();
    if (t == 0) {
        ffn[b]  = r1s[0] + r1s[1] + r1s[2] + r1s[3] + bias[0];
        gate[b] = r2s[0] + r2s[1] + r2s[2] + r2s[3];
    }
}

// ---------------- epilogue 2: softmax over batch + final score ----------------
__global__ __launch_bounds__(TPB)
void score_kernel(const float* __restrict__ ffn,
                  const float* __restrict__ gate,
                  float* __restrict__ out)
{
    const int t = threadIdx.x;  // one block of 256 == BATCH
    __shared__ float buf[4];
    __shared__ float sM, sZ, sS;

    const float g = gate[t];

    float m = g;
    #pragma unroll
    for (int off = 32; off > 0; off >>= 1) m = fmaxf(m, __shfl_down(m, off, 64));
    if ((t & 63) == 0) buf[t >> 6] = m;
    __syncthreads();
    if (t == 0) sM = fmaxf(fmaxf(buf[0], buf[1]), fmaxf(buf[2], buf[3]));
    __syncthreads();

    const float e = expf(g - sM);
    float z = e;
    #pragma unroll
    for (int off = 32; off > 0; off >>= 1) z += __shfl_down(z, off, 64);
    __syncthreads();
    if ((t & 63) == 0) buf[t >> 6] = z;
    __syncthreads();
    if (t == 0) sZ = buf[0] + buf[1] + buf[2] + buf[3];
    __syncthreads();

    float p = e / sZ;           // out_tgn[t]
    float s = p;
    #pragma unroll
    for (int off = 32; off > 0; off >>= 1) s += __shfl_down(s, off, 64);
    __syncthreads();
    if ((t & 63) == 0) buf[t >> 6] = s;
    __syncthreads();
    if (t == 0) sS = buf[0] + buf[1] + buf[2] + buf[3];   // == sum(softmax) ~ 1
    __syncthreads();

    out[t] = ffn[t] * sS;
}

// ---------------- launcher ----------------
extern "C" void kernel_launch(void* const* d_in, const int* in_sizes, int n_in,
                              void* d_out, int out_size, void* d_ws, size_t ws_size,
                              hipStream_t stream)
{
    const float* qe  = (const float*)d_in[0];
    const float* de  = (const float*)d_in[1];
    const float* W1  = (const float*)d_in[2];
    const float* b1  = (const float*)d_in[3];
    const float* Wg  = (const float*)d_in[4];
    const int*   qid = (const int*)d_in[5];
    const int*   did = (const int*)d_in[6];
    float* out = (float*)d_out;

    unsigned* g_hist = (unsigned*)d_ws;
    const size_t hist_bytes = (size_t)BATCH * QL * NB * sizeof(unsigned); // 563,200 B
    float* ffn  = (float*)((char*)d_ws + hist_bytes);
    float* gate = ffn + BATCH;

    hipMemsetAsync(g_hist, 0, hist_bytes, stream);
    sim_hist_kernel<<<BATCH * SEG, TPB, 0, stream>>>(qe, de, qid, did, g_hist);
    ffn_gate_kernel<<<BATCH, TPB, 0, stream>>>(g_hist, W1, b1, qe, Wg, ffn, gate);
    score_kernel<<<1, TPB, 0, stream>>>(ffn, gate, out);
}

// Round 6
// 305.206 us; speedup vs baseline: 1.0731x; 1.0395x over previous
//
#include <hip/hip_runtime.h>
#include <math.h>

#define BATCH 256
#define QL 50
#define EMB 50
#define DL 2000
#define NB 11
#define SEG 2        // d split per batch -> 512 blocks = 256 CU x 2 exactly
#define RPB 1000     // rows per block
#define TPB 256
#define RPT 4        // d rows per thread -> 200 RMW accumulators
#define QPAD 52      // q row padded to 52 floats -> 16B-aligned ds_read_b128
#define SUB 8        // histogram sub-bins (hot-bin atomic spread)

// ---------------- main kernel: cosine sim + histogram + gate dot ----------------
// R3-proven structure (q staged in LDS, ds_read_b128 broadcast, RMW accs ->
// VGPR resident). Scalar-q variants (R4/R5) made the compiler demote accs to
// scratch (VGPR=44, 192us) -- never scalarize q. RPT=4 halves total LDS-pipe
// cycles vs R3's RPT=2 (the measured bottleneck: 650 ds_read x 12cyc/wave).
__global__ __launch_bounds__(TPB, 2)
void sim_hist_kernel(const float* __restrict__ qe,   // [B,QL,EMB]
                     const float* __restrict__ de,   // [B,DL,EMB]
                     const int*   __restrict__ qid,  // [B,QL]
                     const int*   __restrict__ did,  // [B,DL]
                     unsigned*    __restrict__ g_hist, // [B,QL,NB]
                     const float* __restrict__ Wg,   // [QL*EMB]
                     float*       __restrict__ gate) // [B]
{
    const int bid = blockIdx.x;
    const int b   = bid >> 1;
    const int seg = bid & 1;
    const int t   = threadIdx.x;

    __shared__ __align__(16) float s_q[QL * QPAD];   // raw q rows, zero-padded
    __shared__ float    s_qrn[QL];
    __shared__ int      s_qv[QL];
    __shared__ unsigned s_hist[QL * NB * SUB];       // [q][bin][sub]
    __shared__ float    s_red[TPB];

    const float* __restrict__ qbase = qe + (size_t)b * QL * EMB;

    for (int i = t; i < QL * QPAD; i += TPB) {
        const int q = i / QPAD;
        const int e = i - q * QPAD;
        s_q[i] = (e < EMB) ? qbase[q * EMB + e] : 0.f;
    }
    for (int i = t; i < QL * NB * SUB; i += TPB) s_hist[i] = 0u;
    if (t < QL) {
        const float* qr = qbase + t * EMB;
        float ss = 0.f;
        #pragma unroll
        for (int e = 0; e < EMB; ++e) ss = fmaf(qr[e], qr[e], ss);
        s_qrn[t] = 1.0f / (sqrtf(ss) + 1e-8f);
        s_qv[t]  = (qid[(size_t)b * QL + t] > 0) ? 1 : 0;
    }
    __syncthreads();

    // this thread's four d rows (streams 256 apart; clamp+dval for tail)
    const int  l0 = t, l1 = t + 256, l2 = t + 512, l3 = t + 768;
    const bool ok3 = (l3 < RPB);                     // l0..l2 always < 1000
    const int  row0 = seg * RPB + l0;
    const int  row1 = seg * RPB + l1;
    const int  row2 = seg * RPB + l2;
    const int  row3 = seg * RPB + (ok3 ? l3 : 0);
    const float* __restrict__ dr0 = de + ((size_t)b * DL + row0) * EMB;
    const float* __restrict__ dr1 = de + ((size_t)b * DL + row1) * EMB;
    const float* __restrict__ dr2 = de + ((size_t)b * DL + row2) * EMB;
    const float* __restrict__ dr3 = de + ((size_t)b * DL + row3) * EMB;
    const int dval0 = (did[(size_t)b * DL + row0] > 0) ? 1 : 0;
    const int dval1 = (did[(size_t)b * DL + row1] > 0) ? 1 : 0;
    const int dval2 = (did[(size_t)b * DL + row2] > 0) ? 1 : 0;
    const int dval3 = (ok3 && did[(size_t)b * DL + row3] > 0) ? 1 : 0;

    float a0[QL], a1[QL], a2[QL], a3[QL];
    #pragma unroll
    for (int q = 0; q < QL; ++q) { a0[q] = 0.f; a1[q] = 0.f; a2[q] = 0.f; a3[q] = 0.f; }
    float ss0 = 0.f, ss1 = 0.f, ss2 = 0.f, ss3 = 0.f;

    // ---- main loop: 12 e4 steps (e = 0..47); d-transient = 16 regs ----
    #pragma unroll 1
    for (int m = 0; m < 12; ++m) {
        const int e = m * 4;
        const float2 x0 = *(const float2*)(dr0 + e), y0 = *(const float2*)(dr0 + e + 2);
        const float2 x1 = *(const float2*)(dr1 + e), y1 = *(const float2*)(dr1 + e + 2);
        const float2 x2 = *(const float2*)(dr2 + e), y2 = *(const float2*)(dr2 + e + 2);
        const float2 x3 = *(const float2*)(dr3 + e), y3 = *(const float2*)(dr3 + e + 2);
        ss0 = fmaf(x0.x, x0.x, ss0); ss0 = fmaf(x0.y, x0.y, ss0);
        ss0 = fmaf(y0.x, y0.x, ss0); ss0 = fmaf(y0.y, y0.y, ss0);
        ss1 = fmaf(x1.x, x1.x, ss1); ss1 = fmaf(x1.y, x1.y, ss1);
        ss1 = fmaf(y1.x, y1.x, ss1); ss1 = fmaf(y1.y, y1.y, ss1);
        ss2 = fmaf(x2.x, x2.x, ss2); ss2 = fmaf(x2.y, x2.y, ss2);
        ss2 = fmaf(y2.x, y2.x, ss2); ss2 = fmaf(y2.y, y2.y, ss2);
        ss3 = fmaf(x3.x, x3.x, ss3); ss3 = fmaf(x3.y, x3.y, ss3);
        ss3 = fmaf(y3.x, y3.x, ss3); ss3 = fmaf(y3.y, y3.y, ss3);
        #pragma unroll
        for (int q = 0; q < QL; ++q) {
            const float4 qv = *(const float4*)&s_q[q * QPAD + e];  // 1 ds_read_b128
            float t0 = a0[q];
            t0 = fmaf(x0.x, qv.x, t0); t0 = fmaf(x0.y, qv.y, t0);
            t0 = fmaf(y0.x, qv.z, t0); t0 = fmaf(y0.y, qv.w, t0);
            a0[q] = t0;
            float t1 = a1[q];
            t1 = fmaf(x1.x, qv.x, t1); t1 = fmaf(x1.y, qv.y, t1);
            t1 = fmaf(y1.x, qv.z, t1); t1 = fmaf(y1.y, qv.w, t1);
            a1[q] = t1;
            float t2 = a2[q];
            t2 = fmaf(x2.x, qv.x, t2); t2 = fmaf(x2.y, qv.y, t2);
            t2 = fmaf(y2.x, qv.z, t2); t2 = fmaf(y2.y, qv.w, t2);
            a2[q] = t2;
            float t3 = a3[q];
            t3 = fmaf(x3.x, qv.x, t3); t3 = fmaf(x3.y, qv.y, t3);
            t3 = fmaf(y3.x, qv.z, t3); t3 = fmaf(y3.y, qv.w, t3);
            a3[q] = t3;
        }
    }
    // ---- tail: e = 48,49 ----
    {
        const float2 x0 = *(const float2*)(dr0 + 48);
        const float2 x1 = *(const float2*)(dr1 + 48);
        const float2 x2 = *(const float2*)(dr2 + 48);
        const float2 x3 = *(const float2*)(dr3 + 48);
        ss0 = fmaf(x0.x, x0.x, ss0); ss0 = fmaf(x0.y, x0.y, ss0);
        ss1 = fmaf(x1.x, x1.x, ss1); ss1 = fmaf(x1.y, x1.y, ss1);
        ss2 = fmaf(x2.x, x2.x, ss2); ss2 = fmaf(x2.y, x2.y, ss2);
        ss3 = fmaf(x3.x, x3.x, ss3); ss3 = fmaf(x3.y, x3.y, ss3);
        #pragma unroll
        for (int q = 0; q < QL; ++q) {
            const float2 qv = *(const float2*)&s_q[q * QPAD + 48];
            a0[q] = fmaf(x0.y, qv.y, fmaf(x0.x, qv.x, a0[q]));
            a1[q] = fmaf(x1.y, qv.y, fmaf(x1.x, qv.x, a1[q]));
            a2[q] = fmaf(x2.y, qv.y, fmaf(x2.x, qv.x, a2[q]));
            a3[q] = fmaf(x3.y, qv.y, fmaf(x3.x, qv.x, a3[q]));
        }
    }

    const float drn0 = 1.0f / (sqrtf(ss0) + 1e-8f);
    const float drn1 = 1.0f / (sqrtf(ss1) + 1e-8f);
    const float drn2 = 1.0f / (sqrtf(ss2) + 1e-8f);
    const float drn3 = 1.0f / (sqrtf(ss3) + 1e-8f);

    // ---- histogram: 8-way sub-binned LDS atomics (R5: SUB=4 halved
    // conflict cycles; t&7 spreads hot-bin lanes ~3 per sub-counter) ----
    const int sub = t & (SUB - 1);
    #pragma unroll
    for (int q = 0; q < QL; ++q) {
        if (!s_qv[q]) continue;                 // wave-uniform skip
        const float qrn = s_qrn[q];
        {
            const float s  = a0[q] * qrn * drn0;
            const float tt = ((s + 1.000001f) * 0.5f) * 10.0f;
            int bb = (int)tt; bb = bb < 0 ? 0 : (bb > 10 ? 10 : bb);
            if (dval0) atomicAdd(&s_hist[(q * NB + bb) * SUB + sub], 1u);
        }
        {
            const float s  = a1[q] * qrn * drn1;
            const float tt = ((s + 1.000001f) * 0.5f) * 10.0f;
            int bb = (int)tt; bb = bb < 0 ? 0 : (bb > 10 ? 10 : bb);
            if (dval1) atomicAdd(&s_hist[(q * NB + bb) * SUB + sub], 1u);
        }
        {
            const float s  = a2[q] * qrn * drn2;
            const float tt = ((s + 1.000001f) * 0.5f) * 10.0f;
            int bb = (int)tt; bb = bb < 0 ? 0 : (bb > 10 ? 10 : bb);
            if (dval2) atomicAdd(&s_hist[(q * NB + bb) * SUB + sub], 1u);
        }
        {
            const float s  = a3[q] * qrn * drn3;
            const float tt = ((s + 1.000001f) * 0.5f) * 10.0f;
            int bb = (int)tt; bb = bb < 0 ? 0 : (bb > 10 ? 10 : bb);
            if (dval3) atomicAdd(&s_hist[(q * NB + bb) * SUB + sub], 1u);
        }
    }

    __syncthreads();
    for (int i = t; i < QL * NB; i += TPB) {
        unsigned c = 0;
        #pragma unroll
        for (int s = 0; s < SUB; ++s) c += s_hist[i * SUB + s];
        if (c) atomicAdd(&g_hist[(size_t)b * QL * NB + i], c);
    }

    // ---- gate dot (seg 0 only): qe[b]·Wg from LDS-staged q; deterministic ----
    if (seg == 0) {
        float g = 0.f;
        for (int i = t; i < QL * EMB; i += TPB) {
            const int qq = i / EMB;
            const int ee = i - qq * EMB;
            g = fmaf(s_q[qq * QPAD + ee], Wg[i], g);
        }
        s_red[t] = g;
        __syncthreads();
        if (t < 64) {
            float v = s_red[t] + s_red[t + 64] + s_red[t + 128] + s_red[t + 192];
            #pragma unroll
            for (int off = 32; off > 0; off >>= 1) v += __shfl_down(v, off, 64);
            if (t == 0) gate[b] = v;
        }
    }
}

// ---------------- epilogue 1: ffn log-dot per batch ----------------
__global__ __launch_bounds__(TPB)
void ffn_kernel(const unsigned* __restrict__ g_hist,
                const float* __restrict__ W1,
                const float* __restrict__ bias,
                float* __restrict__ ffn)
{
    const int b = blockIdx.x;
    const int t = threadIdx.x;

    float a1 = 0.f;
    for (int i = t; i < QL * NB; i += TPB)
        a1 = fmaf(logf((float)g_hist[(size_t)b * QL * NB + i] + 1e-5f), W1[i], a1);

    #pragma unroll
    for (int off = 32; off > 0; off >>= 1) a1 += __shfl_down(a1, off, 64);
    __shared__ float r1s[4];
    if ((t & 63) == 0) r1s[t >> 6] = a1;
    __syncthreads();
    if (t == 0) ffn[b] = r1s[0] + r1s[1] + r1s[2] + r1s[3] + bias[0];
}

// ---------------- epilogue 2: softmax over batch + final score ----------------
__global__ __launch_bounds__(TPB)
void score_kernel(const float* __restrict__ ffn,
                  const float* __restrict__ gate,
                  float* __restrict__ out)
{
    const int t = threadIdx.x;  // one block of 256 == BATCH
    __shared__ float buf[4];
    __shared__ float sM, sZ, sS;

    const float g = gate[t];

    float m = g;
    #pragma unroll
    for (int off = 32; off > 0; off >>= 1) m = fmaxf(m, __shfl_down(m, off, 64));
    if ((t & 63) == 0) buf[t >> 6] = m;
    __syncthreads();
    if (t == 0) sM = fmaxf(fmaxf(buf[0], buf[1]), fmaxf(buf[2], buf[3]));
    __syncthreads();

    const float e = expf(g - sM);
    float z = e;
    #pragma unroll
    for (int off = 32; off > 0; off >>= 1) z += __shfl_down(z, off, 64);
    __syncthreads();
    if ((t & 63) == 0) buf[t >> 6] = z;
    __syncthreads();
    if (t == 0) sZ = buf[0] + buf[1] + buf[2] + buf[3];
    __syncthreads();

    float p = e / sZ;
    float s = p;
    #pragma unroll
    for (int off = 32; off > 0; off >>= 1) s += __shfl_down(s, off, 64);
    __syncthreads();
    if ((t & 63) == 0) buf[t >> 6] = s;
    __syncthreads();
    if (t == 0) sS = buf[0] + buf[1] + buf[2] + buf[3];
    __syncthreads();

    out[t] = ffn[t] * sS;
}

// ---------------- launcher ----------------
extern "C" void kernel_launch(void* const* d_in, const int* in_sizes, int n_in,
                              void* d_out, int out_size, void* d_ws, size_t ws_size,
                              hipStream_t stream)
{
    const float* qe  = (const float*)d_in[0];
    const float* de  = (const float*)d_in[1];
    const float* W1  = (const float*)d_in[2];
    const float* b1  = (const float*)d_in[3];
    const float* Wg  = (const float*)d_in[4];
    const int*   qid = (const int*)d_in[5];
    const int*   did = (const int*)d_in[6];
    float* out = (float*)d_out;

    unsigned* g_hist = (unsigned*)d_ws;
    const size_t hist_bytes = (size_t)BATCH * QL * NB * sizeof(unsigned); // 563,200 B
    float* ffn  = (float*)((char*)d_ws + hist_bytes);
    float* gate = ffn + BATCH;

    hipMemsetAsync(g_hist, 0, hist_bytes, stream);
    sim_hist_kernel<<<BATCH * SEG, TPB, 0, stream>>>(qe, de, qid, did, g_hist, Wg, gate);
    ffn_kernel<<<BATCH, TPB, 0, stream>>>(g_hist, W1, b1, ffn);
    score_kernel<<<1, TPB, 0, stream>>>(ffn, gate, out);
}